// Round 10
// baseline (499.925 us; speedup 1.0000x reference)
//
#include <hip/hip_runtime.h>
#include <hip/hip_cooperative_groups.h>

namespace cg = cooperative_groups;

#define DFEAT 64
typedef unsigned short bf16_t;

typedef __bf16 bf16x8 __attribute__((ext_vector_type(8)));
typedef float f32x4 __attribute__((ext_vector_type(4)));

#define NPB_SHIFT 7      // 128 nodes per bucket
#define NPB 128
#define BCAP 2048        // bucket capacity (mean ~1280, +21 sigma headroom)
#define ESLICE 2048      // edges per bucketing slice (489 slices)
#define MEAN_STRIDE 72   // LDS mean row stride in bf16 (144 B)
#define COOP_GRID 768    // 3 blocks/CU x 256 CUs — matches __launch_bounds__(256,3)

__device__ __forceinline__ float bflo(unsigned int u) {
    union { unsigned int i; float f; } v;
    v.i = u << 16;
    return v.f;
}
__device__ __forceinline__ float bfhi(unsigned int u) {
    union { unsigned int i; float f; } v;
    v.i = u & 0xFFFF0000u;
    return v.f;
}
__device__ __forceinline__ unsigned short f2bf(float f) {
    unsigned int u = __float_as_uint(f);
    u += 0x7FFFu + ((u >> 16) & 1u);   // round-to-nearest-even
    return (unsigned short)(u >> 16);
}

// ---------------- shared device helpers ----------------

__device__ __forceinline__ void cast_range(const float* __restrict__ x,
                                           bf16_t* __restrict__ xb, int lo, int hi) {
    for (int t = lo + threadIdx.x; t < hi; t += 256) {
        float2 v = ((const float2*)x)[t];
        ushort2 o;
        o.x = f2bf(v.x);
        o.y = f2bf(v.y);
        ((ushort2*)xb)[t] = o;
    }
}

// wf[(f*64 + l)*8 + j], f=kk*4+nt, k=kk*32+(l>>4)*8+j, col=nt*16+(l&15)
__device__ __forceinline__ void prep_w_dev(const float* __restrict__ Ws1,
                                           const float* __restrict__ Wn1,
                                           const float* __restrict__ Ws2,
                                           const float* __restrict__ Wn2,
                                           bf16_t* __restrict__ wf1,
                                           bf16_t* __restrict__ wf2) {
    for (int i = threadIdx.x; i < 16 * 64 * 8; i += 256) {
        int j = i & 7;
        int l = (i >> 3) & 63;
        int f = i >> 9;
        int kk = f >> 2, nt = f & 3;
        int k = kk * 32 + (l >> 4) * 8 + j;
        int col = nt * 16 + (l & 15);
        float v1 = (k < 64) ? Ws1[k * 64 + col] : Wn1[(k - 64) * 64 + col];
        float v2 = (k < 64) ? Ws2[k * 64 + col] : Wn2[(k - 64) * 64 + col];
        wf1[i] = f2bf(v1);
        wf2[i] = f2bf(v2);
    }
}

// bucket a slice of edges by dst>>7; bhist/bcur are 1024-int LDS scratch
__device__ __forceinline__ void bucket_slice(const int* __restrict__ src,
                                             const int* __restrict__ dst,
                                             int* __restrict__ gcur,
                                             int* __restrict__ packbuf,
                                             int n_edges, int nbuck, long ebase,
                                             int* bhist, int* bcur) {
    const int tid = threadIdx.x;
    for (int i = tid; i < 1024; i += 256) bhist[i] = 0;
    __syncthreads();
    for (int i = 0; i < ESLICE / 256; ++i) {
        long e = ebase + i * 256 + tid;
        if (e < n_edges) atomicAdd(&bhist[dst[e] >> NPB_SHIFT], 1);
    }
    __syncthreads();
    for (int bb = tid; bb < nbuck; bb += 256) {
        int h = bhist[bb];
        bcur[bb] = h ? atomicAdd(&gcur[bb], h) : 0;
    }
    __syncthreads();
    for (int i = 0; i < ESLICE / 256; ++i) {
        long e = ebase + i * 256 + tid;
        if (e < n_edges) {
            int d = dst[e];
            int bb = d >> NPB_SHIFT;
            int slot = atomicAdd(&bcur[bb], 1);
            if (slot < BCAP)   // safety; never triggers for this distribution
                packbuf[(size_t)bb * BCAP + slot] = ((d & (NPB - 1)) << 17) | src[e];
        }
    }
}

// LDS counting sort for one bucket: elist per-node-contiguous, hist=deg, scanb=csr
__device__ __forceinline__ void build_sort(const int* __restrict__ pb, int count,
                                           int* elist, int* hist, int* scanb, int* curL) {
    const int tid = threadIdx.x;
    if (tid < NPB) hist[tid] = 0;
    __syncthreads();
    int pkreg[BCAP / 256];
#pragma unroll
    for (int k = 0; k < BCAP / 256; ++k) {
        int i = tid + k * 256;
        if (i < count) {
            int pk = pb[i];
            pkreg[k] = pk;
            atomicAdd(&hist[(pk >> 17) & (NPB - 1)], 1);
        }
    }
    __syncthreads();
    int hv = (tid < NPB) ? hist[tid] : 0;
    if (tid < NPB) scanb[tid] = hv;
    __syncthreads();
    for (int off = 1; off < NPB; off <<= 1) {
        int t = 0;
        if (tid < NPB && tid >= off) t = scanb[tid - off];
        __syncthreads();
        if (tid < NPB) scanb[tid] += t;
        __syncthreads();
    }
    if (tid < NPB) {
        int ex = scanb[tid] - hv;
        scanb[tid] = ex;
        curL[tid]  = ex;
    }
    __syncthreads();
#pragma unroll
    for (int k = 0; k < BCAP / 256; ++k) {
        int i = tid + k * 256;
        if (i < count) {
            int pk = pkreg[k];
            int dl = (pk >> 17) & (NPB - 1);
            int pos = atomicAdd(&curL[dl], 1);
            elist[pos] = pk & 0x1FFFF;
        }
    }
    __syncthreads();
}

// gather + mean -> meanL, then MFMA GEMM + epilogue for bucket b
__device__ __forceinline__ void layer_body(const bf16_t* __restrict__ featb,
                                           const bf16_t* __restrict__ wf,
                                           const float* __restrict__ bias,
                                           float* __restrict__ outf,
                                           bf16_t* __restrict__ outb,
                                           int n_nodes, int do_relu, int b,
                                           int* elist, bf16_t* meanL,
                                           int* hist, int* scanb) {
    const int tid = threadIdx.x;

    // gather: oct (8 lanes) owns 4 nodes, 16 B/lane, 4-deep unroll
    const int oct = tid >> 3;
    const int lo  = tid & 7;
#pragma unroll
    for (int n = 0; n < 4; ++n) {
        int r  = oct * 4 + n;
        int s0 = scanb[r];
        int c  = hist[r];
        float s0f = 0.f, s1f = 0.f, s2f = 0.f, s3f = 0.f;
        float s4f = 0.f, s5f = 0.f, s6f = 0.f, s7f = 0.f;
        int i = 0;
        for (; i + 4 <= c; i += 4) {
            int e0 = elist[s0 + i + 0];
            int e1 = elist[s0 + i + 1];
            int e2 = elist[s0 + i + 2];
            int e3 = elist[s0 + i + 3];
            uint4 u0 = *(const uint4*)(featb + (size_t)e0 * DFEAT + lo * 8);
            uint4 u1 = *(const uint4*)(featb + (size_t)e1 * DFEAT + lo * 8);
            uint4 u2 = *(const uint4*)(featb + (size_t)e2 * DFEAT + lo * 8);
            uint4 u3 = *(const uint4*)(featb + (size_t)e3 * DFEAT + lo * 8);
            s0f += bflo(u0.x) + bflo(u1.x) + bflo(u2.x) + bflo(u3.x);
            s1f += bfhi(u0.x) + bfhi(u1.x) + bfhi(u2.x) + bfhi(u3.x);
            s2f += bflo(u0.y) + bflo(u1.y) + bflo(u2.y) + bflo(u3.y);
            s3f += bfhi(u0.y) + bfhi(u1.y) + bfhi(u2.y) + bfhi(u3.y);
            s4f += bflo(u0.z) + bflo(u1.z) + bflo(u2.z) + bflo(u3.z);
            s5f += bfhi(u0.z) + bfhi(u1.z) + bfhi(u2.z) + bfhi(u3.z);
            s6f += bflo(u0.w) + bflo(u1.w) + bflo(u2.w) + bflo(u3.w);
            s7f += bfhi(u0.w) + bfhi(u1.w) + bfhi(u2.w) + bfhi(u3.w);
        }
        for (; i < c; ++i) {
            int e0 = elist[s0 + i];
            uint4 u = *(const uint4*)(featb + (size_t)e0 * DFEAT + lo * 8);
            s0f += bflo(u.x); s1f += bfhi(u.x);
            s2f += bflo(u.y); s3f += bfhi(u.y);
            s4f += bflo(u.z); s5f += bfhi(u.z);
            s6f += bflo(u.w); s7f += bfhi(u.w);
        }
        float inv = (c > 0) ? 1.0f / (float)c : 0.0f;
        uint4 o;
        o.x = (unsigned int)f2bf(s0f * inv) | ((unsigned int)f2bf(s1f * inv) << 16);
        o.y = (unsigned int)f2bf(s2f * inv) | ((unsigned int)f2bf(s3f * inv) << 16);
        o.z = (unsigned int)f2bf(s4f * inv) | ((unsigned int)f2bf(s5f * inv) << 16);
        o.w = (unsigned int)f2bf(s6f * inv) | ((unsigned int)f2bf(s7f * inv) << 16);
        *(uint4*)(meanL + (size_t)r * MEAN_STRIDE + lo * 8) = o;
    }
    __syncthreads();

    // MFMA GEMM: A = [x-row (global) || mean (LDS)], B frag-major from global
    const int lane = tid & 63;
    const int wave = tid >> 6;
    const int q    = lane >> 4;
    const int cgl  = lane & 15;
    const int nodeBase = b << NPB_SHIFT;

    bf16x8 a[2][4];
#pragma unroll
    for (int slab = 0; slab < 2; ++slab) {
        const int r = wave * 32 + slab * 16 + cgl;
        int nodeA = nodeBase + r;
        if (nodeA >= n_nodes) nodeA = n_nodes - 1;   // clamp; stores predicated
        const bf16_t* xrow = featb + (size_t)nodeA * DFEAT + q * 8;
        a[slab][0] = *(const bf16x8*)(xrow);
        a[slab][1] = *(const bf16x8*)(xrow + 32);
        const bf16_t* mrow = meanL + (size_t)r * MEAN_STRIDE + q * 8;
        a[slab][2] = *(const bf16x8*)(mrow);
        a[slab][3] = *(const bf16x8*)(mrow + 32);
    }

    f32x4 acc[2][4] = {};
#pragma unroll
    for (int nt = 0; nt < 4; ++nt) {
        bf16x8 bf[4];
#pragma unroll
        for (int kk = 0; kk < 4; ++kk)
            bf[kk] = *(const bf16x8*)(wf + (size_t)((kk * 4 + nt) * 64 + lane) * 8);
#pragma unroll
        for (int slab = 0; slab < 2; ++slab) {
#pragma unroll
            for (int kk = 0; kk < 4; ++kk)
                acc[slab][nt] = __builtin_amdgcn_mfma_f32_16x16x32_bf16(
                    a[slab][kk], bf[kk], acc[slab][nt], 0, 0, 0);
        }
    }

#pragma unroll
    for (int slab = 0; slab < 2; ++slab) {
#pragma unroll
        for (int nt = 0; nt < 4; ++nt) {
            const float bl = bias[nt * 16 + cgl];
#pragma unroll
            for (int reg = 0; reg < 4; ++reg) {
                int node = nodeBase + wave * 32 + slab * 16 + q * 4 + reg;
                if (node >= n_nodes) continue;
                float v = acc[slab][nt][reg] + bl;
                if (do_relu) v = fmaxf(v, 0.0f);
                if (outf) outf[(size_t)node * DFEAT + nt * 16 + cgl] = v;
                else      outb[(size_t)node * DFEAT + nt * 16 + cgl] = f2bf(v);
            }
        }
    }
}

// ---------------- cooperative single-kernel pipeline ----------------
__global__ __launch_bounds__(256, 3) void sage_all(
        const int* __restrict__ src, const int* __restrict__ dst,
        const float* __restrict__ x,
        const float* __restrict__ Ws1, const float* __restrict__ Wn1,
        const float* __restrict__ bias1,
        const float* __restrict__ Ws2, const float* __restrict__ Wn2,
        const float* __restrict__ bias2,
        float* __restrict__ out,
        int* __restrict__ gcur, bf16_t* __restrict__ wf1, bf16_t* __restrict__ wf2,
        int* __restrict__ packbuf, bf16_t* __restrict__ xb, bf16_t* __restrict__ hb,
        int n_nodes, int n_edges, int n_half, int nbuck) {
    __shared__ int    elist[BCAP];                   //  8192 B
    __shared__ bf16_t meanL[NPB * MEAN_STRIDE];      // 18432 B
    __shared__ int    hist[NPB];
    __shared__ int    scanb[NPB];
    __shared__ int    curL[NPB];

    cg::grid_group grid = cg::this_grid();
    const int tid  = threadIdx.x;
    const int blk  = blockIdx.x;
    const int nblk = gridDim.x;

    // P0: zero gcur | cast x->bf16 | W -> frag-major
    if (blk == 0)
        for (int i = tid; i < 1024; i += 256) gcur[i] = 0;
    {
        int per = (n_half + nblk - 1) / nblk;
        int lo  = blk * per;
        int hi  = min(lo + per, n_half);
        cast_range(x, xb, lo, hi);
    }
    if (blk == nblk - 1)
        prep_w_dev(Ws1, Wn1, Ws2, Wn2, wf1, wf2);
    grid.sync();

    // P1: bucket edges (489 slices)
    {
        int eblk = (n_edges + ESLICE - 1) / ESLICE;
        if (blk < eblk)
            bucket_slice(src, dst, gcur, packbuf, n_edges, nbuck,
                         (long)blk * ESLICE, (int*)meanL, ((int*)meanL) + 1024);
    }
    grid.sync();

    // P2: layer 1 (sort + gather + MFMA per bucket, grid-stride)
    for (int b = blk; b < nbuck; b += nblk) {
        build_sort(packbuf + (size_t)b * BCAP, min(gcur[b], BCAP),
                   elist, hist, scanb, curL);
        layer_body(xb, wf1, bias1, nullptr, hb, n_nodes, 1, b,
                   elist, meanL, hist, scanb);
        __syncthreads();
    }
    grid.sync();

    // P3: layer 2 (rebuild sort, gather hb, MFMA)
    for (int b = blk; b < nbuck; b += nblk) {
        build_sort(packbuf + (size_t)b * BCAP, min(gcur[b], BCAP),
                   elist, hist, scanb, curL);
        layer_body(hb, wf2, bias2, out, nullptr, n_nodes, 0, b,
                   elist, meanL, hist, scanb);
        __syncthreads();
    }
}

// ---------------- fallback pipeline (R8 structure, shared helpers) ----------
__global__ __launch_bounds__(256) void prep_all_fb(const int* __restrict__ src,
                                                   const int* __restrict__ dst,
                                                   int* __restrict__ gcur,
                                                   int* __restrict__ packbuf,
                                                   int n_edges, int nbuck,
                                                   const float* __restrict__ x,
                                                   bf16_t* __restrict__ xb, int n_half,
                                                   const float* __restrict__ Ws1,
                                                   const float* __restrict__ Wn1,
                                                   const float* __restrict__ Ws2,
                                                   const float* __restrict__ Wn2,
                                                   bf16_t* __restrict__ wf1,
                                                   bf16_t* __restrict__ wf2,
                                                   int ab, int cb) {
    __shared__ int bhist[1024];
    __shared__ int bcur[1024];
    const int blk = blockIdx.x;
    if (blk < ab) {
        bucket_slice(src, dst, gcur, packbuf, n_edges, nbuck,
                     (long)blk * ESLICE, bhist, bcur);
    } else if (blk < ab + cb) {
        int lo = (blk - ab) * 256;
        cast_range(x, xb, lo, min(lo + 256, n_half));
    } else {
        prep_w_dev(Ws1, Wn1, Ws2, Wn2, wf1, wf2);
    }
}

__global__ __launch_bounds__(256) void fused_layer_fb(const bf16_t* __restrict__ featb,
                                                      const int* __restrict__ gcur,
                                                      const int* __restrict__ packbuf,
                                                      const bf16_t* __restrict__ wf,
                                                      const float* __restrict__ bias,
                                                      float* __restrict__ outf,
                                                      bf16_t* __restrict__ outb,
                                                      int n_nodes, int do_relu) {
    __shared__ int    elist[BCAP];
    __shared__ bf16_t meanL[NPB * MEAN_STRIDE];
    __shared__ int    hist[NPB];
    __shared__ int    scanb[NPB];
    __shared__ int    curL[NPB];
    const int b = blockIdx.x;
    build_sort(packbuf + (size_t)b * BCAP, min(gcur[b], BCAP),
               elist, hist, scanb, curL);
    layer_body(featb, wf, bias, outf, outb, n_nodes, do_relu, b,
               elist, meanL, hist, scanb);
}

// -------------------------------------------------------------------------

extern "C" void kernel_launch(void* const* d_in, const int* in_sizes, int n_in,
                              void* d_out, int out_size, void* d_ws, size_t ws_size,
                              hipStream_t stream) {
    const float* x       = (const float*)d_in[0];
    const int*   src     = (const int*)d_in[1];
    const int*   dst     = (const int*)d_in[2];
    const float* Wself1  = (const float*)d_in[3];
    const float* Wneigh1 = (const float*)d_in[4];
    const float* b1      = (const float*)d_in[5];
    const float* Wself2  = (const float*)d_in[6];
    const float* Wneigh2 = (const float*)d_in[7];
    const float* b2      = (const float*)d_in[8];
    float* out = (float*)d_out;

    int n_nodes = in_sizes[0] / DFEAT;
    int n_edges = in_sizes[1];
    int nbuck   = (n_nodes + NPB - 1) >> NPB_SHIFT;       // 782
    int n_half  = n_nodes * DFEAT / 2;

    // Workspace: gcur[1024] | wf1[8192] | wf2[8192] | packbuf | xb | hb
    int* gcur       = (int*)d_ws;
    bf16_t* wf1     = (bf16_t*)(gcur + 1024);
    bf16_t* wf2     = wf1 + 16 * 64 * 8;
    int* packbuf    = (int*)(wf2 + 16 * 64 * 8);
    bf16_t* xb      = (bf16_t*)(packbuf + (size_t)nbuck * BCAP);
    bf16_t* hb      = xb + (size_t)n_nodes * DFEAT;

    void* args[] = {
        &src, &dst, &x, &Wself1, &Wneigh1, &b1, &Wself2, &Wneigh2, &b2, &out,
        &gcur, &wf1, &wf2, &packbuf, &xb, &hb,
        &n_nodes, &n_edges, &n_half, &nbuck
    };
    hipError_t err = hipLaunchCooperativeKernel((const void*)sage_all,
                                                dim3(COOP_GRID), dim3(256),
                                                args, 0, stream);
    if (err != hipSuccess) {
        (void)hipGetLastError();   // clear sticky error; use fallback pipeline
        int ab = (n_edges + ESLICE - 1) / ESLICE;     // 489
        int cb = (n_half + 255) / 256;
        hipMemsetAsync(gcur, 0, 1024 * sizeof(int), stream);
        prep_all_fb<<<ab + cb + 1, 256, 0, stream>>>(src, dst, gcur, packbuf,
                                                     n_edges, nbuck, x, xb, n_half,
                                                     Wself1, Wneigh1, Wself2, Wneigh2,
                                                     wf1, wf2, ab, cb);
        fused_layer_fb<<<nbuck, 256, 0, stream>>>(xb, gcur, packbuf, wf1, b1,
                                                  nullptr, hb, n_nodes, 1);
        fused_layer_fb<<<nbuck, 256, 0, stream>>>(hb, gcur, packbuf, wf2, b2,
                                                  out, nullptr, n_nodes, 0);
    }
}

// Round 11
// 178.548 us; speedup vs baseline: 2.7999x; 2.7999x over previous
//
#include <hip/hip_runtime.h>

#define DFEAT 64
typedef unsigned short bf16_t;

typedef __bf16 bf16x8 __attribute__((ext_vector_type(8)));
typedef float f32x4 __attribute__((ext_vector_type(4)));

#define NPB_SHIFT 7      // 128 nodes per bucket
#define NPB 128
#define BCAP 2048        // bucket capacity (mean ~1280 + pad <=512, max ~1700)
#define ESLICE 2048      // edges per bucketing block (489 blocks)
#define MEAN_STRIDE 72   // LDS mean row stride in bf16 (144 B)

__device__ __forceinline__ float bflo(unsigned int u) {
    union { unsigned int i; float f; } v;
    v.i = u << 16;
    return v.f;
}
__device__ __forceinline__ float bfhi(unsigned int u) {
    union { unsigned int i; float f; } v;
    v.i = u & 0xFFFF0000u;
    return v.f;
}
__device__ __forceinline__ unsigned short f2bf(float f) {
    unsigned int u = __float_as_uint(f);
    u += 0x7FFFu + ((u >> 16) & 1u);   // round-to-nearest-even
    return (unsigned short)(u >> 16);
}

// ---------------- prep: bucketing | x->bf16 cast | W frag-major --------------
// blocks [0, ab): bucket 2048-edge slices by dst>>7; pack=(dst&127)<<17|src
// blocks [ab, ab+cb): cast x -> bf16
// block ab+cb: W -> frag-major bf16; zero row N of xb and hb (pad-row target)
__global__ __launch_bounds__(256) void prep_all(const int* __restrict__ src,
                                                const int* __restrict__ dst,
                                                int* __restrict__ gcur,
                                                int* __restrict__ packbuf,
                                                int n_edges, int nbuck,
                                                const float* __restrict__ x,
                                                bf16_t* __restrict__ xb,
                                                bf16_t* __restrict__ hb, int n_half,
                                                const float* __restrict__ Ws1,
                                                const float* __restrict__ Wn1,
                                                const float* __restrict__ Ws2,
                                                const float* __restrict__ Wn2,
                                                bf16_t* __restrict__ wf1,
                                                bf16_t* __restrict__ wf2,
                                                int ab, int cb, int n_nodes) {
    const int tid = threadIdx.x;
    const int blk = blockIdx.x;
    if (blk < ab) {
        __shared__ int bhist[1024];
        __shared__ int bcur[1024];
        const long ebase = (long)blk * ESLICE;
        for (int i = tid; i < 1024; i += 256) bhist[i] = 0;
        __syncthreads();
        for (int i = 0; i < ESLICE / 256; ++i) {
            long e = ebase + i * 256 + tid;
            if (e < n_edges) atomicAdd(&bhist[dst[e] >> NPB_SHIFT], 1);
        }
        __syncthreads();
        for (int bb = tid; bb < nbuck; bb += 256) {
            int h = bhist[bb];
            bcur[bb] = h ? atomicAdd(&gcur[bb], h) : 0;
        }
        __syncthreads();
        for (int i = 0; i < ESLICE / 256; ++i) {
            long e = ebase + i * 256 + tid;
            if (e < n_edges) {
                int d = dst[e];
                int bb = d >> NPB_SHIFT;
                int slot = atomicAdd(&bcur[bb], 1);
                if (slot < BCAP)   // safety; never triggers for this distribution
                    packbuf[(size_t)bb * BCAP + slot] = ((d & (NPB - 1)) << 17) | src[e];
            }
        }
    } else if (blk < ab + cb) {
        int t = (blk - ab) * 256 + tid;
        if (t < n_half) {
            float2 v = ((const float2*)x)[t];
            ushort2 o;
            o.x = f2bf(v.x);
            o.y = f2bf(v.y);
            ((ushort2*)xb)[t] = o;
        }
    } else {
        // wf[(f*64+l)*8+j], f=kk*4+nt, k=kk*32+(l>>4)*8+j, col=nt*16+(l&15)
        for (int i = tid; i < 16 * 64 * 8; i += 256) {
            int j = i & 7;
            int l = (i >> 3) & 63;
            int f = i >> 9;
            int kk = f >> 2, nt = f & 3;
            int k = kk * 32 + (l >> 4) * 8 + j;
            int col = nt * 16 + (l & 15);
            float v1 = (k < 64) ? Ws1[k * 64 + col] : Wn1[(k - 64) * 64 + col];
            float v2 = (k < 64) ? Ws2[k * 64 + col] : Wn2[(k - 64) * 64 + col];
            wf1[i] = f2bf(v1);
            wf2[i] = f2bf(v2);
        }
        if (tid < DFEAT) {   // zero the pad row (index n_nodes) in both feats
            xb[(size_t)n_nodes * DFEAT + tid] = 0;
            hb[(size_t)n_nodes * DFEAT + tid] = 0;
        }
    }
}

// ---------------- fused layer: padded counting sort -> gather -> MFMA --------
// Per-node segments in elist are 4-aligned and padded to multiples of 4 with
// the zero-row index -> index reads are one aligned int4 LDS load, no scalar
// remainder, 8-deep main loop for MLP.
__global__ __launch_bounds__(256) void fused_layer(const bf16_t* __restrict__ featb,
                                                   const int* __restrict__ gcur,
                                                   const int* __restrict__ packbuf,
                                                   const bf16_t* __restrict__ wf,
                                                   const float* __restrict__ bias,
                                                   float* __restrict__ outf,
                                                   bf16_t* __restrict__ outb,
                                                   int n_nodes, int do_relu, int zrow) {
    __shared__ int    elist[BCAP];                   //  8192 B
    __shared__ bf16_t meanL[NPB * MEAN_STRIDE];      // 18432 B
    __shared__ int    hist[NPB];
    __shared__ int    scanb[NPB];
    __shared__ int    curL[NPB];

    const int tid = threadIdx.x;
    const int b   = blockIdx.x;

    if (tid < NPB) hist[tid] = 0;
    __syncthreads();

    const int count = min(gcur[b], BCAP);
    const int* pb = packbuf + (size_t)b * BCAP;

    // P1: cache edges in registers + LDS int histogram
    int pkreg[BCAP / 256];
#pragma unroll
    for (int k = 0; k < BCAP / 256; ++k) {
        int i = tid + k * 256;
        if (i < count) {
            int pk = pb[i];
            pkreg[k] = pk;
            atomicAdd(&hist[(pk >> 17) & (NPB - 1)], 1);
        }
    }
    __syncthreads();

    // P2: exclusive scan over PADDED counts (each segment 4-aligned)
    int hv = (tid < NPB) ? hist[tid] : 0;
    int cp = (hv + 3) & ~3;
    if (tid < NPB) scanb[tid] = cp;
    __syncthreads();
    for (int off = 1; off < NPB; off <<= 1) {
        int t = 0;
        if (tid < NPB && tid >= off) t = scanb[tid - off];
        __syncthreads();
        if (tid < NPB) scanb[tid] += t;
        __syncthreads();
    }
    if (tid < NPB) {
        int ex = scanb[tid] - cp;
        scanb[tid] = ex;
        curL[tid]  = ex;
    }
    __syncthreads();

    // P3: scatter src ids; then pad tail of each segment with zero-row idx
#pragma unroll
    for (int k = 0; k < BCAP / 256; ++k) {
        int i = tid + k * 256;
        if (i < count) {
            int pk = pkreg[k];
            int dl = (pk >> 17) & (NPB - 1);
            int pos = atomicAdd(&curL[dl], 1);
            if (pos < BCAP) elist[pos] = pk & 0x1FFFF;
        }
    }
    __syncthreads();
    if (tid < NPB) {
        int s0 = scanb[tid];
        int c  = hist[tid];
        int ce = s0 + ((c + 3) & ~3);
        for (int p = s0 + c; p < ce && p < BCAP; ++p) elist[p] = zrow;
    }
    __syncthreads();

    // P4: oct-owner gather, aligned int4 index loads, 8-deep main loop
    const int oct = tid >> 3;
    const int lo  = tid & 7;
#pragma unroll
    for (int n = 0; n < 4; ++n) {
        int r  = oct * 4 + n;
        int s0 = scanb[r];
        int c  = hist[r];
        int cpd = (c + 3) & ~3;
        float s0f = 0.f, s1f = 0.f, s2f = 0.f, s3f = 0.f;
        float s4f = 0.f, s5f = 0.f, s6f = 0.f, s7f = 0.f;
        int i = 0;
        for (; i + 8 <= cpd; i += 8) {
            int4 ea = *(const int4*)(elist + s0 + i);
            int4 eb = *(const int4*)(elist + s0 + i + 4);
            uint4 u0 = *(const uint4*)(featb + (size_t)ea.x * DFEAT + lo * 8);
            uint4 u1 = *(const uint4*)(featb + (size_t)ea.y * DFEAT + lo * 8);
            uint4 u2 = *(const uint4*)(featb + (size_t)ea.z * DFEAT + lo * 8);
            uint4 u3 = *(const uint4*)(featb + (size_t)ea.w * DFEAT + lo * 8);
            uint4 u4 = *(const uint4*)(featb + (size_t)eb.x * DFEAT + lo * 8);
            uint4 u5 = *(const uint4*)(featb + (size_t)eb.y * DFEAT + lo * 8);
            uint4 u6 = *(const uint4*)(featb + (size_t)eb.z * DFEAT + lo * 8);
            uint4 u7 = *(const uint4*)(featb + (size_t)eb.w * DFEAT + lo * 8);
            s0f += bflo(u0.x) + bflo(u1.x) + bflo(u2.x) + bflo(u3.x)
                 + bflo(u4.x) + bflo(u5.x) + bflo(u6.x) + bflo(u7.x);
            s1f += bfhi(u0.x) + bfhi(u1.x) + bfhi(u2.x) + bfhi(u3.x)
                 + bfhi(u4.x) + bfhi(u5.x) + bfhi(u6.x) + bfhi(u7.x);
            s2f += bflo(u0.y) + bflo(u1.y) + bflo(u2.y) + bflo(u3.y)
                 + bflo(u4.y) + bflo(u5.y) + bflo(u6.y) + bflo(u7.y);
            s3f += bfhi(u0.y) + bfhi(u1.y) + bfhi(u2.y) + bfhi(u3.y)
                 + bfhi(u4.y) + bfhi(u5.y) + bfhi(u6.y) + bfhi(u7.y);
            s4f += bflo(u0.z) + bflo(u1.z) + bflo(u2.z) + bflo(u3.z)
                 + bflo(u4.z) + bflo(u5.z) + bflo(u6.z) + bflo(u7.z);
            s5f += bfhi(u0.z) + bfhi(u1.z) + bfhi(u2.z) + bfhi(u3.z)
                 + bfhi(u4.z) + bfhi(u5.z) + bfhi(u6.z) + bfhi(u7.z);
            s6f += bflo(u0.w) + bflo(u1.w) + bflo(u2.w) + bflo(u3.w)
                 + bflo(u4.w) + bflo(u5.w) + bflo(u6.w) + bflo(u7.w);
            s7f += bfhi(u0.w) + bfhi(u1.w) + bfhi(u2.w) + bfhi(u3.w)
                 + bfhi(u4.w) + bfhi(u5.w) + bfhi(u6.w) + bfhi(u7.w);
        }
        if (i < cpd) {
            int4 ea = *(const int4*)(elist + s0 + i);
            uint4 u0 = *(const uint4*)(featb + (size_t)ea.x * DFEAT + lo * 8);
            uint4 u1 = *(const uint4*)(featb + (size_t)ea.y * DFEAT + lo * 8);
            uint4 u2 = *(const uint4*)(featb + (size_t)ea.z * DFEAT + lo * 8);
            uint4 u3 = *(const uint4*)(featb + (size_t)ea.w * DFEAT + lo * 8);
            s0f += bflo(u0.x) + bflo(u1.x) + bflo(u2.x) + bflo(u3.x);
            s1f += bfhi(u0.x) + bfhi(u1.x) + bfhi(u2.x) + bfhi(u3.x);
            s2f += bflo(u0.y) + bflo(u1.y) + bflo(u2.y) + bflo(u3.y);
            s3f += bfhi(u0.y) + bfhi(u1.y) + bfhi(u2.y) + bfhi(u3.y);
            s4f += bflo(u0.z) + bflo(u1.z) + bflo(u2.z) + bflo(u3.z);
            s5f += bfhi(u0.z) + bfhi(u1.z) + bfhi(u2.z) + bfhi(u3.z);
            s6f += bflo(u0.w) + bflo(u1.w) + bflo(u2.w) + bflo(u3.w);
            s7f += bfhi(u0.w) + bfhi(u1.w) + bfhi(u2.w) + bfhi(u3.w);
        }
        float inv = (c > 0) ? 1.0f / (float)c : 0.0f;
        uint4 o;
        o.x = (unsigned int)f2bf(s0f * inv) | ((unsigned int)f2bf(s1f * inv) << 16);
        o.y = (unsigned int)f2bf(s2f * inv) | ((unsigned int)f2bf(s3f * inv) << 16);
        o.z = (unsigned int)f2bf(s4f * inv) | ((unsigned int)f2bf(s5f * inv) << 16);
        o.w = (unsigned int)f2bf(s6f * inv) | ((unsigned int)f2bf(s7f * inv) << 16);
        *(uint4*)(meanL + (size_t)r * MEAN_STRIDE + lo * 8) = o;
    }
    __syncthreads();

    // P5: MFMA GEMM: A = [x-row (global) || mean (LDS)], B frag-major global
    const int lane = tid & 63;
    const int wave = tid >> 6;
    const int q    = lane >> 4;
    const int cgl  = lane & 15;
    const int nodeBase = b << NPB_SHIFT;

    bf16x8 a[2][4];
#pragma unroll
    for (int slab = 0; slab < 2; ++slab) {
        const int r = wave * 32 + slab * 16 + cgl;
        int nodeA = nodeBase + r;
        if (nodeA >= n_nodes) nodeA = n_nodes - 1;   // clamp; stores predicated
        const bf16_t* xrow = featb + (size_t)nodeA * DFEAT + q * 8;
        a[slab][0] = *(const bf16x8*)(xrow);
        a[slab][1] = *(const bf16x8*)(xrow + 32);
        const bf16_t* mrow = meanL + (size_t)r * MEAN_STRIDE + q * 8;
        a[slab][2] = *(const bf16x8*)(mrow);
        a[slab][3] = *(const bf16x8*)(mrow + 32);
    }

    f32x4 acc[2][4] = {};
#pragma unroll
    for (int nt = 0; nt < 4; ++nt) {
        bf16x8 bf[4];
#pragma unroll
        for (int kk = 0; kk < 4; ++kk)
            bf[kk] = *(const bf16x8*)(wf + (size_t)((kk * 4 + nt) * 64 + lane) * 8);
#pragma unroll
        for (int slab = 0; slab < 2; ++slab) {
#pragma unroll
            for (int kk = 0; kk < 4; ++kk)
                acc[slab][nt] = __builtin_amdgcn_mfma_f32_16x16x32_bf16(
                    a[slab][kk], bf[kk], acc[slab][nt], 0, 0, 0);
        }
    }

#pragma unroll
    for (int slab = 0; slab < 2; ++slab) {
#pragma unroll
        for (int nt = 0; nt < 4; ++nt) {
            const float bl = bias[nt * 16 + cgl];
#pragma unroll
            for (int reg = 0; reg < 4; ++reg) {
                int node = nodeBase + wave * 32 + slab * 16 + q * 4 + reg;
                if (node >= n_nodes) continue;
                float v = acc[slab][nt][reg] + bl;
                if (do_relu) v = fmaxf(v, 0.0f);
                if (outf) outf[(size_t)node * DFEAT + nt * 16 + cgl] = v;
                else      outb[(size_t)node * DFEAT + nt * 16 + cgl] = f2bf(v);
            }
        }
    }
}

// -------------------------------------------------------------------------

extern "C" void kernel_launch(void* const* d_in, const int* in_sizes, int n_in,
                              void* d_out, int out_size, void* d_ws, size_t ws_size,
                              hipStream_t stream) {
    const float* x       = (const float*)d_in[0];
    const int*   src     = (const int*)d_in[1];
    const int*   dst     = (const int*)d_in[2];
    const float* Wself1  = (const float*)d_in[3];
    const float* Wneigh1 = (const float*)d_in[4];
    const float* b1      = (const float*)d_in[5];
    const float* Wself2  = (const float*)d_in[6];
    const float* Wneigh2 = (const float*)d_in[7];
    const float* b2      = (const float*)d_in[8];
    float* out = (float*)d_out;

    int n_nodes = in_sizes[0] / DFEAT;
    int n_edges = in_sizes[1];
    int nbuck   = (n_nodes + NPB - 1) >> NPB_SHIFT;       // 782
    int n_half  = n_nodes * DFEAT / 2;

    // Workspace: gcur[1024] | wf1[8192] | wf2[8192] | packbuf | xb[(N+1)*D] | hb[(N+1)*D]
    int* gcur       = (int*)d_ws;
    bf16_t* wf1     = (bf16_t*)(gcur + 1024);
    bf16_t* wf2     = wf1 + 16 * 64 * 8;
    int* packbuf    = (int*)(wf2 + 16 * 64 * 8);
    bf16_t* xb      = (bf16_t*)(packbuf + (size_t)nbuck * BCAP);
    bf16_t* hb      = xb + (size_t)(n_nodes + 1) * DFEAT;

    int ab = (n_edges + ESLICE - 1) / ESLICE;             // 489
    int cb = (n_half + 255) / 256;

    hipMemsetAsync(gcur, 0, 1024 * sizeof(int), stream);
    prep_all<<<ab + cb + 1, 256, 0, stream>>>(src, dst, gcur, packbuf,
                                              n_edges, nbuck, x, xb, hb, n_half,
                                              Wself1, Wneigh1, Wself2, Wneigh2,
                                              wf1, wf2, ab, cb, n_nodes);

    fused_layer<<<nbuck, 256, 0, stream>>>(xb, gcur, packbuf, wf1, b1,
                                           nullptr, hb, n_nodes, 1, n_nodes);
    fused_layer<<<nbuck, 256, 0, stream>>>(hb, gcur, packbuf, wf2, b2,
                                           out, nullptr, n_nodes, 0, n_nodes);
}